// Round 1
// baseline (1480.691 us; speedup 1.0000x reference)
//
#include <hip/hip_runtime.h>

#define NUM_CODES 8192
#define CODE_DIM  64
#define BATCH     65536
#define TR 128   // rows per block (argmin kernel)
#define TC 128   // codes per tile

// ---------------------------------------------------------------------------
// Kernel 0: per-code squared norms csq[c] = sum_k codebook[c][k]^2
// ---------------------------------------------------------------------------
__global__ void csq_kernel(const float* __restrict__ cb, float* __restrict__ csq) {
    int c = blockIdx.x * blockDim.x + threadIdx.x;
    if (c >= NUM_CODES) return;
    const float4* row = reinterpret_cast<const float4*>(cb + (size_t)c * CODE_DIM);
    float s = 0.f;
#pragma unroll
    for (int i = 0; i < CODE_DIM / 4; ++i) {
        float4 v = row[i];
        s = fmaf(v.x, v.x, s); s = fmaf(v.y, v.y, s);
        s = fmaf(v.z, v.z, s); s = fmaf(v.w, v.w, s);
    }
    csq[c] = s;
}

// ---------------------------------------------------------------------------
// Kernel 1: fused distance + argmin.
// Block: 256 threads = 16(tx:codes) x 16(ty:rows), 8x8 micro-tile per thread.
// Block tile: 128 rows x 128 codes per iteration over 64 code-tiles.
// dist = (zsq - 2*dot) + csq, matching the reference formula's structure.
// ---------------------------------------------------------------------------
__global__ __launch_bounds__(256, 2)
void argmin_kernel(const float* __restrict__ z, const float* __restrict__ cb,
                   const float* __restrict__ csq, float* __restrict__ codes_out) {
    __shared__ float zT[CODE_DIM][TR];   // 32 KB, transposed z tile
    __shared__ float cT[CODE_DIM][TC];   // 32 KB, transposed codebook tile

    const int tid = threadIdx.x;
    const int tx = tid & 15;       // code group
    const int ty = tid >> 4;       // row group
    const int row0 = blockIdx.x * TR;

    // ---- stage zT (once per block), coalesced global reads ----
#pragma unroll
    for (int it = 0; it < 8; ++it) {
        int id = it * 256 + tid;            // 2048 float4 chunks
        int r  = id >> 4;                   // 0..127
        int kc = id & 15;                   // float4 chunk within row
        float4 v = reinterpret_cast<const float4*>(z + (size_t)(row0 + r) * CODE_DIM)[kc];
        zT[kc * 4 + 0][r] = v.x; zT[kc * 4 + 1][r] = v.y;
        zT[kc * 4 + 2][r] = v.z; zT[kc * 4 + 3][r] = v.w;
    }
    __syncthreads();

    // ---- per-thread row squared norms (8 rows) ----
    float zsq[8];
#pragma unroll
    for (int r = 0; r < 8; ++r) {
        float s = 0.f;
        for (int k = 0; k < CODE_DIM; ++k) {
            float v = zT[k][ty * 8 + r];
            s = fmaf(v, v, s);
        }
        zsq[r] = s;
    }

    float minv[8];
    int   mini[8];
#pragma unroll
    for (int r = 0; r < 8; ++r) { minv[r] = 3.4e38f; mini[r] = 0; }

#pragma unroll 1
    for (int ct = 0; ct < NUM_CODES / TC; ++ct) {
        __syncthreads();   // protect cT from previous tile's readers
        // ---- stage cT: coalesced loads (16 consecutive threads cover one code row)
#pragma unroll
        for (int j8 = 0; j8 < 8; ++j8) {
            int c  = j8 * 16 + (tid >> 4);   // 0..127
            int kc = tid & 15;
            float4 v = reinterpret_cast<const float4*>(
                           cb + (size_t)(ct * TC + c) * CODE_DIM)[kc];
            cT[kc * 4 + 0][c] = v.x; cT[kc * 4 + 1][c] = v.y;
            cT[kc * 4 + 2][c] = v.z; cT[kc * 4 + 3][c] = v.w;
        }
        __syncthreads();

        float acc[8][8];
#pragma unroll
        for (int r = 0; r < 8; ++r)
#pragma unroll
            for (int c = 0; c < 8; ++c) acc[r][c] = 0.f;

#pragma unroll 4
        for (int k = 0; k < CODE_DIM; ++k) {
            float a[8], b[8];
            *reinterpret_cast<float4*>(&a[0]) = *reinterpret_cast<const float4*>(&zT[k][ty * 8]);
            *reinterpret_cast<float4*>(&a[4]) = *reinterpret_cast<const float4*>(&zT[k][ty * 8 + 4]);
            *reinterpret_cast<float4*>(&b[0]) = *reinterpret_cast<const float4*>(&cT[k][tx * 8]);
            *reinterpret_cast<float4*>(&b[4]) = *reinterpret_cast<const float4*>(&cT[k][tx * 8 + 4]);
#pragma unroll
            for (int r = 0; r < 8; ++r)
#pragma unroll
                for (int c = 0; c < 8; ++c)
                    acc[r][c] = fmaf(a[r], b[c], acc[r][c]);
        }

        // ---- epilogue: distances + running argmin ----
        float cs[8];
        *reinterpret_cast<float4*>(&cs[0]) =
            *reinterpret_cast<const float4*>(csq + ct * TC + tx * 8);
        *reinterpret_cast<float4*>(&cs[4]) =
            *reinterpret_cast<const float4*>(csq + ct * TC + tx * 8 + 4);
#pragma unroll
        for (int r = 0; r < 8; ++r) {
#pragma unroll
            for (int c = 0; c < 8; ++c) {
                float d = fmaf(-2.f, acc[r][c], zsq[r]) + cs[c];
                int idx = ct * TC + tx * 8 + c;
                if (d < minv[r]) { minv[r] = d; mini[r] = idx; }
            }
        }
    }

    // ---- reduce across the 16 code-threads (lanes ty*16+tx within wave) ----
#pragma unroll
    for (int m = 1; m < 16; m <<= 1) {
#pragma unroll
        for (int r = 0; r < 8; ++r) {
            float ov = __shfl_xor(minv[r], m, 64);
            int   oi = __shfl_xor(mini[r], m, 64);
            if (ov < minv[r] || (ov == minv[r] && oi < mini[r])) {
                minv[r] = ov; mini[r] = oi;
            }
        }
    }
    if (tx == 0) {
#pragma unroll
        for (int r = 0; r < 8; ++r)
            codes_out[row0 + ty * 8 + r] = (float)mini[r];
    }
}

// ---------------------------------------------------------------------------
// Kernel 2: gather z_q_st, loss partial sum, counts histogram, assigned_sum.
// 4 threads per row, 16 dims each.
// ---------------------------------------------------------------------------
__global__ void gather_kernel(const float* __restrict__ z, const float* __restrict__ cb,
                              const float* __restrict__ codes_f,
                              float* __restrict__ zq_out,
                              float* __restrict__ ws_counts, float* __restrict__ ws_asum,
                              float* __restrict__ ws_loss) {
    int gid  = blockIdx.x * 256 + threadIdx.x;
    int row  = gid >> 2;
    int part = gid & 3;
    int c = (int)codes_f[row];
    const float4* zp = reinterpret_cast<const float4*>(z + (size_t)row * CODE_DIM) + part * 4;
    const float4* cp = reinterpret_cast<const float4*>(cb + (size_t)c  * CODE_DIM) + part * 4;
    float4* op = reinterpret_cast<float4*>(zq_out + (size_t)row * CODE_DIM) + part * 4;
    float* asp = ws_asum + (size_t)c * CODE_DIM + part * 16;

    float lsum = 0.f;
#pragma unroll
    for (int i = 0; i < 4; ++i) {
        float4 zv = zp[i], cv = cp[i];
        float4 o;   // straight-through: z + (z_q - z), replicated in f32
        o.x = zv.x + (cv.x - zv.x); o.y = zv.y + (cv.y - zv.y);
        o.z = zv.z + (cv.z - zv.z); o.w = zv.w + (cv.w - zv.w);
        op[i] = o;
        float dx = zv.x - cv.x, dy = zv.y - cv.y, dz = zv.z - cv.z, dw = zv.w - cv.w;
        lsum = fmaf(dx, dx, lsum); lsum = fmaf(dy, dy, lsum);
        lsum = fmaf(dz, dz, lsum); lsum = fmaf(dw, dw, lsum);
        atomicAdd(asp + i * 4 + 0, zv.x); atomicAdd(asp + i * 4 + 1, zv.y);
        atomicAdd(asp + i * 4 + 2, zv.z); atomicAdd(asp + i * 4 + 3, zv.w);
    }
    // wave-level loss reduction, one atomic per wave
#pragma unroll
    for (int m = 1; m < 64; m <<= 1) lsum += __shfl_xor(lsum, m, 64);
    if ((threadIdx.x & 63) == 0) atomicAdd(ws_loss, lsum);
    if (part == 0) atomicAdd(&ws_counts[c], 1.0f);
}

// ---------------------------------------------------------------------------
// Kernel 3: EMA finalize + losses.
// ---------------------------------------------------------------------------
__global__ void finalize_kernel(const float* __restrict__ ema_count,
                                const float* __restrict__ ema_weight,
                                const float* __restrict__ usage,
                                const float* __restrict__ ws_counts,
                                const float* __restrict__ ws_asum,
                                const float* __restrict__ ws_loss,
                                float* __restrict__ out_codebook, float* __restrict__ out_count,
                                float* __restrict__ out_weight,   float* __restrict__ out_usage,
                                float* __restrict__ out_losses) {
    int gid = blockIdx.x * 256 + threadIdx.x;   // K*D = 524288
    if (gid >= NUM_CODES * CODE_DIM) return;
    int c = gid >> 6;
    float cnt  = ws_counts[c];
    float ncnt = 0.99f * ema_count[c] + 0.01f * cnt;
    float nw   = 0.99f * ema_weight[gid] + 0.01f * ws_asum[gid];
    out_weight[gid]   = nw;
    out_codebook[gid] = nw / (ncnt + 1e-5f);
    if ((gid & 63) == 0) {
        out_count[c] = ncnt;
        out_usage[c] = usage[c] + cnt;
    }
    if (gid == 0) {
        float s = ws_loss[0] * (1.0f / ((float)BATCH * (float)CODE_DIM));
        out_losses[0] = s;                    // commitment_loss
        out_losses[1] = s;                    // codebook_loss (same value)
        out_losses[2] = fmaf(0.25f, s, s);    // vq_loss
    }
}

// ---------------------------------------------------------------------------
extern "C" void kernel_launch(void* const* d_in, const int* in_sizes, int n_in,
                              void* d_out, int out_size, void* d_ws, size_t ws_size,
                              hipStream_t stream) {
    const float* z     = (const float*)d_in[0];   // [65536,64]
    const float* cb    = (const float*)d_in[1];   // [8192,64]
    const float* emac  = (const float*)d_in[2];   // [8192]
    const float* emaw  = (const float*)d_in[3];   // [8192,64]
    const float* usage = (const float*)d_in[4];   // [8192]

    float* out = (float*)d_out;
    float* o_zq    = out;                                  // 4194304
    float* o_codes = out + 4194304;                        // 65536
    float* o_loss  = out + 4194304 + 65536;                // 3 scalars
    float* o_cb    = o_loss + 3;                           // 524288
    float* o_cnt   = o_cb + 524288;                        // 8192
    float* o_w     = o_cnt + 8192;                         // 524288
    float* o_use   = o_w + 524288;                         // 8192

    float* ws       = (float*)d_ws;
    float* ws_csq   = ws;                   // 8192
    float* ws_cnt   = ws + 8192;            // 8192
    float* ws_asum  = ws + 16384;           // 524288
    float* ws_loss  = ws + 16384 + 524288;  // 1

    // zero counts + asum + loss accumulator (ws is poisoned before each launch)
    hipMemsetAsync((char*)d_ws + 8192 * sizeof(float), 0,
                   (size_t)(8192 + 524288 + 1) * sizeof(float), stream);

    csq_kernel<<<NUM_CODES / 128, 128, 0, stream>>>(cb, ws_csq);
    argmin_kernel<<<BATCH / TR, 256, 0, stream>>>(z, cb, ws_csq, o_codes);
    gather_kernel<<<BATCH * 4 / 256, 256, 0, stream>>>(z, cb, o_codes, o_zq,
                                                       ws_cnt, ws_asum, ws_loss);
    finalize_kernel<<<NUM_CODES * CODE_DIM / 256, 256, 0, stream>>>(
        emac, emaw, usage, ws_cnt, ws_asum, ws_loss,
        o_cb, o_cnt, o_w, o_use, o_loss);
}

// Round 3
// 729.944 us; speedup vs baseline: 2.0285x; 2.0285x over previous
//
#include <hip/hip_runtime.h>
#include <stdint.h>

#define NUM_CODES 8192
#define CODE_DIM  64
#define BATCH     65536

typedef float    f32x4 __attribute__((ext_vector_type(4)));
typedef _Float16 half8 __attribute__((ext_vector_type(8)));

#define MFMA(a, b, c) __builtin_amdgcn_mfma_f32_16x16x32_f16(a, b, c, 0, 0, 0)

// ---- workspace layout (byte offsets); total = 2,162,692 B (== proven bound)
#define WS_CSQ_OFF   0u           // 8192 f32            [0,       32768)
#define WS_CNT_OFF   32768u       // 8192 f32            [32768,   65536)
#define WS_CBH_OFF   65536u       // 8192*64 f16 hi      [65536,   1114112)
#define WS_CBL_OFF   1114112u     // 8192*64 f16 lo*2048 [1114112, 2162688)
#define WS_LOSS_OFF  2162688u     // 1 f32               [2162688, 2162692)

__device__ __forceinline__ void gload16(const void* g, void* l) {
    __builtin_amdgcn_global_load_lds(
        (const __attribute__((address_space(1))) void*)g,
        (__attribute__((address_space(3))) void*)l,
        16, 0, 0);
}

// ---------------------------------------------------------------------------
// Prep: split codebook into f16 hi + 2048*lo with chunk-XOR swizzle, + csq.
// 8 threads per code row (one 16B chunk of 8 f16 each).
// ---------------------------------------------------------------------------
__global__ void split_cb_kernel(const float* __restrict__ cb,
                                char* __restrict__ cbh, char* __restrict__ cbl,
                                float* __restrict__ csq) {
    int gid  = blockIdx.x * 256 + threadIdx.x;   // 65536 total
    int code = gid >> 3;
    int c    = gid & 7;                          // 16B chunk within row
    const float* p = cb + (size_t)code * CODE_DIM + c * 8;
    f32x4 u0 = *(const f32x4*)p;
    f32x4 u1 = *(const f32x4*)(p + 4);
    half8 h, lo;
    float ssq = 0.f;
#pragma unroll
    for (int i = 0; i < 4; ++i) {
        float v0 = u0[i], v1 = u1[i];
        ssq = fmaf(v0, v0, ssq); ssq = fmaf(v1, v1, ssq);
        _Float16 h0 = (_Float16)v0, h1 = (_Float16)v1;
        h[i] = h0;     h[i + 4] = h1;
        lo[i]     = (_Float16)((v0 - (float)h0) * 2048.f);
        lo[i + 4] = (_Float16)((v1 - (float)h1) * 2048.f);
    }
    int slot = code * 8 + (c ^ (code & 7));      // swizzled 16B-chunk position
    ((half8*)cbh)[slot] = h;
    ((half8*)cbl)[slot] = lo;
    // row-sum of squares across the 8 chunk-threads (consecutive lanes)
    ssq += __shfl_xor(ssq, 1, 64);
    ssq += __shfl_xor(ssq, 2, 64);
    ssq += __shfl_xor(ssq, 4, 64);
    if (c == 0) csq[code] = ssq;
}

// ---------------------------------------------------------------------------
// Fused distance + argmin via split-f16 MFMA.
// Block: 256 thr = 4 waves (2 row-halves x 2 code-halves). Block tile:
// 128 rows x 128 codes/iter over 64 code-tiles. Wave tile 64x64.
// score = csq - 2*z.cb  (zsq dropped: row-constant, argmin-invariant).
// dot split: a = ah + al/2048, b = bh + bl/2048 (lo pre-scaled x2048);
// dot = ah.bh + (ah.bl + al.bh)/2048 + (al.bl)/2048^2  -- exact to ~2^-22.
// ---------------------------------------------------------------------------
__global__ __launch_bounds__(256, 2)
void argmin_mfma_kernel(const float* __restrict__ z, const char* __restrict__ cbh,
                        const char* __restrict__ cbl, const float* __restrict__ csq,
                        float* __restrict__ codes_out) {
    __shared__ __align__(16) char lds[65536];    // 2 x (16K hi + 16K lo)
    const int tid    = threadIdx.x;
    const int lane   = tid & 63;
    const int w      = tid >> 6;
    const int wr     = w >> 1, wc = w & 1;
    const int lane_r = lane & 15, lg = lane >> 4;
    const int brow   = blockIdx.x * 128 + wr * 64;

    // ---- A fragments: z rows scaled by -2, split hi + 2048*lo, in regs ----
    half8 ah[4][2], al[4][2];
#pragma unroll
    for (int m = 0; m < 4; ++m) {
        const float* zp = z + (size_t)(brow + m * 16 + lane_r) * CODE_DIM;
#pragma unroll
        for (int ks = 0; ks < 2; ++ks) {
            f32x4 u0 = *(const f32x4*)(zp + ks * 32 + lg * 8);
            f32x4 u1 = *(const f32x4*)(zp + ks * 32 + lg * 8 + 4);
            half8 h, lo;
#pragma unroll
            for (int i = 0; i < 4; ++i) {
                float a0 = -2.f * u0[i];
                _Float16 h0 = (_Float16)a0;
                h[i] = h0; lo[i] = (_Float16)((a0 - (float)h0) * 2048.f);
                float a1 = -2.f * u1[i];
                _Float16 h1 = (_Float16)a1;
                h[i + 4] = h1; lo[i + 4] = (_Float16)((a1 - (float)h1) * 2048.f);
            }
            ah[m][ks] = h; al[m][ks] = lo;
        }
    }

    float minv[16]; int mini[16];
#pragma unroll
    for (int i = 0; i < 16; ++i) { minv[i] = 3.4e38f; mini[i] = 0; }

    // ---- prologue: stage tile 0 (each wave stages one 8KB quarter) ----
    {
        const char* src = (w < 2) ? (cbh + (size_t)w * 8192)
                                  : (cbl + (size_t)(w - 2) * 8192);
        char* dst = lds + w * 8192;
#pragma unroll
        for (int i = 0; i < 8; ++i)
            gload16(src + i * 1024 + lane * 16, dst + i * 1024);
    }
    __syncthreads();

    int buf = 0;
#pragma unroll 1
    for (int t = 0; t < NUM_CODES / 128; ++t) {
        // stage next tile into the other buffer (async, drains at barrier)
        if (t < NUM_CODES / 128 - 1) {
            const char* src = (w < 2)
                ? (cbh + (size_t)(t + 1) * 16384 + w * 8192)
                : (cbl + (size_t)(t + 1) * 16384 + (w - 2) * 8192);
            char* dst = lds + (buf ^ 1) * 32768 + w * 8192;
#pragma unroll
            for (int i = 0; i < 8; ++i)
                gload16(src + i * 1024 + lane * 16, dst + i * 1024);
        }

        const char* bh_p = lds + buf * 32768;
        const char* bl_p = bh_p + 16384;
        const int cbase = t * 128 + wc * 64;
#pragma unroll
        for (int n = 0; n < 4; ++n) {
            const int rt  = wc * 64 + n * 16 + lane_r;     // LDS tile row
            const int sw  = rt & 7;
            const int rb  = rt * 128;
            half8 bh0 = *(const half8*)(bh_p + rb + (((0 + lg) ^ sw) << 4));
            half8 bh1 = *(const half8*)(bh_p + rb + (((4 + lg) ^ sw) << 4));
            half8 bl0 = *(const half8*)(bl_p + rb + (((0 + lg) ^ sw) << 4));
            half8 bl1 = *(const half8*)(bl_p + rb + (((4 + lg) ^ sw) << 4));
            float cs  = csq[cbase + n * 16 + lane_r];
            f32x4 cini = {cs, cs, cs, cs};
            f32x4 zero = {0.f, 0.f, 0.f, 0.f};
            int idxv = cbase + n * 16 + lane_r;
#pragma unroll
            for (int m = 0; m < 4; ++m) {
                f32x4 hi = MFMA(ah[m][0], bh0, cini);
                hi = MFMA(ah[m][1], bh1, hi);
                f32x4 mid = MFMA(ah[m][0], bl0, zero);
                mid = MFMA(al[m][0], bh0, mid);
                mid = MFMA(ah[m][1], bl1, mid);
                mid = MFMA(al[m][1], bh1, mid);
                f32x4 lolo = MFMA(al[m][0], bl0, zero);
                lolo = MFMA(al[m][1], bl1, lolo);
#pragma unroll
                for (int j = 0; j < 4; ++j) {
                    // s = hi + mid/2048 + lolo/2048^2
                    float s = fmaf(fmaf(lolo[j], 4.8828125e-4f, mid[j]),
                                   4.8828125e-4f, hi[j]);
                    bool lt = s < minv[m * 4 + j];
                    minv[m * 4 + j] = lt ? s : minv[m * 4 + j];
                    mini[m * 4 + j] = lt ? idxv : mini[m * 4 + j];
                }
            }
        }
        __syncthreads();   // drains gload_lds (vmcnt) + protects buffers
        buf ^= 1;
    }

    // ---- reduce across the 16 code-lanes of each row group ----
#pragma unroll
    for (int s = 1; s < 16; s <<= 1) {
#pragma unroll
        for (int i = 0; i < 16; ++i) {
            float ov = __shfl_xor(minv[i], s, 64);
            int   oi = __shfl_xor(mini[i], s, 64);
            if (ov < minv[i] || (ov == minv[i] && oi < mini[i])) {
                minv[i] = ov; mini[i] = oi;
            }
        }
    }

    // ---- merge the two code-half waves via LDS, write codes ----
    float* smv = (float*)lds;
    int*   smi = (int*)(lds + 512);
    if (wc == 1 && lane_r == 0) {
#pragma unroll
        for (int m = 0; m < 4; ++m)
#pragma unroll
            for (int j = 0; j < 4; ++j) {
                int rl = wr * 64 + m * 16 + lg * 4 + j;
                smv[rl] = minv[m * 4 + j]; smi[rl] = mini[m * 4 + j];
            }
    }
    __syncthreads();
    if (wc == 0 && lane_r == 0) {
#pragma unroll
        for (int m = 0; m < 4; ++m)
#pragma unroll
            for (int j = 0; j < 4; ++j) {
                int rl = wr * 64 + m * 16 + lg * 4 + j;
                float mv = minv[m * 4 + j]; int mi = mini[m * 4 + j];
                float ov = smv[rl]; int oi = smi[rl];
                if (ov < mv || (ov == mv && oi < mi)) { mv = ov; mi = oi; }
                codes_out[blockIdx.x * 128 + rl] = (float)mi;
            }
    }
}

// ---------------------------------------------------------------------------
// Gather z_q_st, loss partial sum, counts histogram, assigned_sum (into the
// out_weight region of d_out, pre-zeroed -- saves 2MB of ws).
// ---------------------------------------------------------------------------
__global__ void gather_kernel(const float* __restrict__ z, const float* __restrict__ cb,
                              const float* __restrict__ codes_f,
                              float* __restrict__ zq_out,
                              float* __restrict__ ws_counts, float* __restrict__ asum,
                              float* __restrict__ ws_loss) {
    int gid  = blockIdx.x * 256 + threadIdx.x;
    int row  = gid >> 2;
    int part = gid & 3;
    int c = (int)codes_f[row];
    const float4* zp = reinterpret_cast<const float4*>(z + (size_t)row * CODE_DIM) + part * 4;
    const float4* cp = reinterpret_cast<const float4*>(cb + (size_t)c  * CODE_DIM) + part * 4;
    float4* op = reinterpret_cast<float4*>(zq_out + (size_t)row * CODE_DIM) + part * 4;
    float* asp = asum + (size_t)c * CODE_DIM + part * 16;

    float lsum = 0.f;
#pragma unroll
    for (int i = 0; i < 4; ++i) {
        float4 zv = zp[i], cv = cp[i];
        float4 o;   // straight-through: z + (z_q - z)
        o.x = zv.x + (cv.x - zv.x); o.y = zv.y + (cv.y - zv.y);
        o.z = zv.z + (cv.z - zv.z); o.w = zv.w + (cv.w - zv.w);
        op[i] = o;
        float dx = zv.x - cv.x, dy = zv.y - cv.y, dz = zv.z - cv.z, dw = zv.w - cv.w;
        lsum = fmaf(dx, dx, lsum); lsum = fmaf(dy, dy, lsum);
        lsum = fmaf(dz, dz, lsum); lsum = fmaf(dw, dw, lsum);
        atomicAdd(asp + i * 4 + 0, zv.x); atomicAdd(asp + i * 4 + 1, zv.y);
        atomicAdd(asp + i * 4 + 2, zv.z); atomicAdd(asp + i * 4 + 3, zv.w);
    }
#pragma unroll
    for (int m = 1; m < 64; m <<= 1) lsum += __shfl_xor(lsum, m, 64);
    if ((threadIdx.x & 63) == 0) atomicAdd(ws_loss, lsum);
    if (part == 0) atomicAdd(&ws_counts[c], 1.0f);
}

// ---------------------------------------------------------------------------
// EMA finalize + losses. asum aliases out_weight: each thread reads its own
// element then overwrites it (same thread -> no race).
// ---------------------------------------------------------------------------
__global__ void finalize_kernel(const float* __restrict__ ema_count,
                                const float* __restrict__ ema_weight,
                                const float* __restrict__ usage,
                                const float* __restrict__ ws_counts,
                                const float* __restrict__ ws_loss,
                                float* __restrict__ out_codebook, float* __restrict__ out_count,
                                float* __restrict__ out_weight,   float* __restrict__ out_usage,
                                float* __restrict__ out_losses) {
    int gid = blockIdx.x * 256 + threadIdx.x;
    if (gid >= NUM_CODES * CODE_DIM) return;
    int c = gid >> 6;
    float cnt  = ws_counts[c];
    float ncnt = 0.99f * ema_count[c] + 0.01f * cnt;
    float nw   = 0.99f * ema_weight[gid] + 0.01f * out_weight[gid];  // asum alias
    out_weight[gid]   = nw;
    out_codebook[gid] = nw / (ncnt + 1e-5f);
    if ((gid & 63) == 0) {
        out_count[c] = ncnt;
        out_usage[c] = usage[c] + cnt;
    }
    if (gid == 0) {
        float s = ws_loss[0] * (1.0f / ((float)BATCH * (float)CODE_DIM));
        out_losses[0] = s;
        out_losses[1] = s;
        out_losses[2] = fmaf(0.25f, s, s);
    }
}

// ---------------------------------------------------------------------------
extern "C" void kernel_launch(void* const* d_in, const int* in_sizes, int n_in,
                              void* d_out, int out_size, void* d_ws, size_t ws_size,
                              hipStream_t stream) {
    const float* z     = (const float*)d_in[0];
    const float* cb    = (const float*)d_in[1];
    const float* emac  = (const float*)d_in[2];
    const float* emaw  = (const float*)d_in[3];
    const float* usage = (const float*)d_in[4];

    float* out = (float*)d_out;
    float* o_zq    = out;                    // 4194304
    float* o_codes = out + 4194304;          // 65536
    float* o_loss  = out + 4194304 + 65536;  // 3
    float* o_cb    = o_loss + 3;             // 524288
    float* o_cnt   = o_cb + 524288;          // 8192
    float* o_w     = o_cnt + 8192;           // 524288 (doubles as asum acc)
    float* o_use   = o_w + 524288;           // 8192

    char*  wsb     = (char*)d_ws;
    float* ws_csq  = (float*)(wsb + WS_CSQ_OFF);
    float* ws_cnt  = (float*)(wsb + WS_CNT_OFF);
    char*  ws_cbh  = wsb + WS_CBH_OFF;
    char*  ws_cbl  = wsb + WS_CBL_OFF;
    float* ws_loss = (float*)(wsb + WS_LOSS_OFF);

    // zero accumulators (ws/d_out are poisoned before each timed launch)
    hipMemsetAsync(wsb + WS_CNT_OFF, 0, 32768, stream);                 // counts
    hipMemsetAsync(wsb + WS_LOSS_OFF, 0, 4, stream);                    // loss
    hipMemsetAsync(o_w, 0, (size_t)524288 * sizeof(float), stream);     // asum

    split_cb_kernel<<<256, 256, 0, stream>>>(cb, ws_cbh, ws_cbl, ws_csq);
    argmin_mfma_kernel<<<512, 256, 0, stream>>>(z, ws_cbh, ws_cbl, ws_csq, o_codes);
    gather_kernel<<<BATCH * 4 / 256, 256, 0, stream>>>(z, cb, o_codes, o_zq,
                                                       ws_cnt, o_w, ws_loss);
    finalize_kernel<<<NUM_CODES * CODE_DIM / 256, 256, 0, stream>>>(
        emac, emaw, usage, ws_cnt, ws_loss,
        o_cb, o_cnt, o_w, o_use, o_loss);
}

// Round 5
// 503.448 us; speedup vs baseline: 2.9411x; 1.4499x over previous
//
#include <hip/hip_runtime.h>
#include <stdint.h>

#define NUM_CODES 8192
#define CODE_DIM  64
#define BATCH     65536

typedef float    f32x4 __attribute__((ext_vector_type(4)));
typedef _Float16 half8 __attribute__((ext_vector_type(8)));
typedef uint32_t u32;

#define MFMA(a, b, c) __builtin_amdgcn_mfma_f32_16x16x32_f16(a, b, c, 0, 0, 0)

// ---- workspace layout (byte offsets); total = 2,162,692 B (== proven bound)
#define WS_CSQ_OFF   0u           // 8192 f32
#define WS_CNT_OFF   32768u       // 8192 f32 (histogram, zeroed)
#define WS_CBH_OFF   65536u       // 8192*64 f16 hi, chunk-swizzled
#define WS_CBL_OFF   1114112u     // 8192*64 f16 lo*2048
#define WS_LOSS_OFF  2162688u     // 1 f32

__device__ __forceinline__ void gload16(const void* g, void* l) {
    __builtin_amdgcn_global_load_lds(
        (const __attribute__((address_space(1))) void*)g,
        (__attribute__((address_space(3))) void*)l,
        16, 0, 0);
}

// ---------------------------------------------------------------------------
// Prep: split codebook into f16 hi + 2048*lo with chunk-XOR swizzle, + csq.
// ---------------------------------------------------------------------------
__global__ void split_cb_kernel(const float* __restrict__ cb,
                                char* __restrict__ cbh, char* __restrict__ cbl,
                                float* __restrict__ csq) {
    int gid  = blockIdx.x * 256 + threadIdx.x;   // 65536 total
    int code = gid >> 3;
    int c    = gid & 7;
    const float* p = cb + (size_t)code * CODE_DIM + c * 8;
    f32x4 u0 = *(const f32x4*)p;
    f32x4 u1 = *(const f32x4*)(p + 4);
    half8 h, lo;
    float ssq = 0.f;
#pragma unroll
    for (int i = 0; i < 4; ++i) {
        float v0 = u0[i], v1 = u1[i];
        ssq = fmaf(v0, v0, ssq); ssq = fmaf(v1, v1, ssq);
        _Float16 h0 = (_Float16)v0, h1 = (_Float16)v1;
        h[i] = h0;     h[i + 4] = h1;
        lo[i]     = (_Float16)((v0 - (float)h0) * 2048.f);
        lo[i + 4] = (_Float16)((v1 - (float)h1) * 2048.f);
    }
    int slot = code * 8 + (c ^ (code & 7));
    ((half8*)cbh)[slot] = h;
    ((half8*)cbl)[slot] = lo;
    ssq += __shfl_xor(ssq, 1, 64);
    ssq += __shfl_xor(ssq, 2, 64);
    ssq += __shfl_xor(ssq, 4, 64);
    if (c == 0) csq[code] = ssq;
}

// ---------------------------------------------------------------------------
// Fused distance + argmin via split-f16 MFMA (+ fused counts histogram).
// ---------------------------------------------------------------------------
__global__ __launch_bounds__(256, 2)
void argmin_mfma_kernel(const float* __restrict__ z, const char* __restrict__ cbh,
                        const char* __restrict__ cbl, const float* __restrict__ csq,
                        float* __restrict__ codes_out, float* __restrict__ ws_counts) {
    __shared__ __align__(16) char lds[65536];
    const int tid    = threadIdx.x;
    const int lane   = tid & 63;
    const int w      = tid >> 6;
    const int wr     = w >> 1, wc = w & 1;
    const int lane_r = lane & 15, lg = lane >> 4;
    const int brow   = blockIdx.x * 128 + wr * 64;

    half8 ah[4][2], al[4][2];
#pragma unroll
    for (int m = 0; m < 4; ++m) {
        const float* zp = z + (size_t)(brow + m * 16 + lane_r) * CODE_DIM;
#pragma unroll
        for (int ks = 0; ks < 2; ++ks) {
            f32x4 u0 = *(const f32x4*)(zp + ks * 32 + lg * 8);
            f32x4 u1 = *(const f32x4*)(zp + ks * 32 + lg * 8 + 4);
            half8 h, lo;
#pragma unroll
            for (int i = 0; i < 4; ++i) {
                float a0 = -2.f * u0[i];
                _Float16 h0 = (_Float16)a0;
                h[i] = h0; lo[i] = (_Float16)((a0 - (float)h0) * 2048.f);
                float a1 = -2.f * u1[i];
                _Float16 h1 = (_Float16)a1;
                h[i + 4] = h1; lo[i + 4] = (_Float16)((a1 - (float)h1) * 2048.f);
            }
            ah[m][ks] = h; al[m][ks] = lo;
        }
    }

    float minv[16]; int mini[16];
#pragma unroll
    for (int i = 0; i < 16; ++i) { minv[i] = 3.4e38f; mini[i] = 0; }

    {
        const char* src = (w < 2) ? (cbh + (size_t)w * 8192)
                                  : (cbl + (size_t)(w - 2) * 8192);
        char* dst = lds + w * 8192;
#pragma unroll
        for (int i = 0; i < 8; ++i)
            gload16(src + i * 1024 + lane * 16, dst + i * 1024);
    }
    __syncthreads();

    int buf = 0;
#pragma unroll 1
    for (int t = 0; t < NUM_CODES / 128; ++t) {
        if (t < NUM_CODES / 128 - 1) {
            const char* src = (w < 2)
                ? (cbh + (size_t)(t + 1) * 16384 + w * 8192)
                : (cbl + (size_t)(t + 1) * 16384 + (w - 2) * 8192);
            char* dst = lds + (buf ^ 1) * 32768 + w * 8192;
#pragma unroll
            for (int i = 0; i < 8; ++i)
                gload16(src + i * 1024 + lane * 16, dst + i * 1024);
        }

        const char* bh_p = lds + buf * 32768;
        const char* bl_p = bh_p + 16384;
        const int cbase = t * 128 + wc * 64;
#pragma unroll
        for (int n = 0; n < 4; ++n) {
            const int rt  = wc * 64 + n * 16 + lane_r;
            const int sw  = rt & 7;
            const int rb  = rt * 128;
            half8 bh0 = *(const half8*)(bh_p + rb + (((0 + lg) ^ sw) << 4));
            half8 bh1 = *(const half8*)(bh_p + rb + (((4 + lg) ^ sw) << 4));
            half8 bl0 = *(const half8*)(bl_p + rb + (((0 + lg) ^ sw) << 4));
            half8 bl1 = *(const half8*)(bl_p + rb + (((4 + lg) ^ sw) << 4));
            float cs  = csq[cbase + n * 16 + lane_r];
            f32x4 cini = {cs, cs, cs, cs};
            f32x4 zero = {0.f, 0.f, 0.f, 0.f};
            int idxv = cbase + n * 16 + lane_r;
#pragma unroll
            for (int m = 0; m < 4; ++m) {
                f32x4 hi = MFMA(ah[m][0], bh0, cini);
                hi = MFMA(ah[m][1], bh1, hi);
                f32x4 mid = MFMA(ah[m][0], bl0, zero);
                mid = MFMA(al[m][0], bh0, mid);
                mid = MFMA(ah[m][1], bl1, mid);
                mid = MFMA(al[m][1], bh1, mid);
                f32x4 lolo = MFMA(al[m][0], bl0, zero);
                lolo = MFMA(al[m][1], bl1, lolo);
#pragma unroll
                for (int j = 0; j < 4; ++j) {
                    float s = fmaf(fmaf(lolo[j], 4.8828125e-4f, mid[j]),
                                   4.8828125e-4f, hi[j]);
                    bool lt = s < minv[m * 4 + j];
                    minv[m * 4 + j] = lt ? s : minv[m * 4 + j];
                    mini[m * 4 + j] = lt ? idxv : mini[m * 4 + j];
                }
            }
        }
        __syncthreads();
        buf ^= 1;
    }

#pragma unroll
    for (int s = 1; s < 16; s <<= 1) {
#pragma unroll
        for (int i = 0; i < 16; ++i) {
            float ov = __shfl_xor(minv[i], s, 64);
            int   oi = __shfl_xor(mini[i], s, 64);
            if (ov < minv[i] || (ov == minv[i] && oi < mini[i])) {
                minv[i] = ov; mini[i] = oi;
            }
        }
    }

    float* smv = (float*)lds;
    int*   smi = (int*)(lds + 512);
    if (wc == 1 && lane_r == 0) {
#pragma unroll
        for (int m = 0; m < 4; ++m)
#pragma unroll
            for (int j = 0; j < 4; ++j) {
                int rl = wr * 64 + m * 16 + lg * 4 + j;
                smv[rl] = minv[m * 4 + j]; smi[rl] = mini[m * 4 + j];
            }
    }
    __syncthreads();
    if (wc == 0 && lane_r == 0) {
#pragma unroll
        for (int m = 0; m < 4; ++m)
#pragma unroll
            for (int j = 0; j < 4; ++j) {
                int rl = wr * 64 + m * 16 + lg * 4 + j;
                float mv = minv[m * 4 + j]; int mi = mini[m * 4 + j];
                float ov = smv[rl]; int oi = smi[rl];
                if (ov < mv || (ov == mv && oi < mi)) { mv = ov; mi = oi; }
                codes_out[blockIdx.x * 128 + rl] = (float)mi;
                atomicAdd(&ws_counts[mi], 1.0f);   // fused histogram
            }
    }
}

// ---------------------------------------------------------------------------
// Exclusive scan of counts -> offsets[8193] + cursor copy. 1 block, 1024 thr.
// ---------------------------------------------------------------------------
__global__ void scan_kernel(const float* __restrict__ cnt,
                            u32* __restrict__ offsets, u32* __restrict__ cursor) {
    __shared__ u32 tsum[1024];
    int t = threadIdx.x;
    u32 v[8], s = 0;
#pragma unroll
    for (int i = 0; i < 8; ++i) { v[i] = (u32)cnt[t * 8 + i]; s += v[i]; }
    tsum[t] = s;
    __syncthreads();
    for (int off = 1; off < 1024; off <<= 1) {
        u32 x = (t >= off) ? tsum[t - off] : 0;
        __syncthreads();
        tsum[t] += x;
        __syncthreads();
    }
    u32 base = (t > 0) ? tsum[t - 1] : 0;
#pragma unroll
    for (int i = 0; i < 8; ++i) {
        offsets[t * 8 + i] = base;
        cursor [t * 8 + i] = base;
        base += v[i];
    }
    if (t == 1023) offsets[8192] = base;
}

// ---------------------------------------------------------------------------
// Scatter: place row into sorted-by-code order (1 atomic/row), fused with
// z_q straight-through write + loss partial sum. 4 threads per row.
// ---------------------------------------------------------------------------
__global__ void scatter_kernel(const float* __restrict__ z, const float* __restrict__ cb,
                               const float* __restrict__ codes_f,
                               float* __restrict__ zq_out,
                               u32* __restrict__ cursor, u32* __restrict__ rowidx,
                               float* __restrict__ ws_loss) {
    int gid  = blockIdx.x * 256 + threadIdx.x;
    int row  = gid >> 2;
    int part = gid & 3;
    int c = (int)codes_f[row];
    const float4* zp = reinterpret_cast<const float4*>(z + (size_t)row * CODE_DIM) + part * 4;
    const float4* cp = reinterpret_cast<const float4*>(cb + (size_t)c  * CODE_DIM) + part * 4;
    float4* op = reinterpret_cast<float4*>(zq_out + (size_t)row * CODE_DIM) + part * 4;

    float lsum = 0.f;
#pragma unroll
    for (int i = 0; i < 4; ++i) {
        float4 zv = zp[i], cv = cp[i];
        float4 o;   // straight-through: z + (z_q - z)
        o.x = zv.x + (cv.x - zv.x); o.y = zv.y + (cv.y - zv.y);
        o.z = zv.z + (cv.z - zv.z); o.w = zv.w + (cv.w - zv.w);
        op[i] = o;
        float dx = zv.x - cv.x, dy = zv.y - cv.y, dz = zv.z - cv.z, dw = zv.w - cv.w;
        lsum = fmaf(dx, dx, lsum); lsum = fmaf(dy, dy, lsum);
        lsum = fmaf(dz, dz, lsum); lsum = fmaf(dw, dw, lsum);
    }
#pragma unroll
    for (int m = 1; m < 64; m <<= 1) lsum += __shfl_xor(lsum, m, 64);
    if ((threadIdx.x & 63) == 0) atomicAdd(ws_loss, lsum);
    if (part == 0) {
        u32 pos = atomicAdd(&cursor[c], 1u);
        rowidx[pos] = (u32)row;
    }
}

// ---------------------------------------------------------------------------
// Segmented sum: one wave per code, lane = dim. Zero atomics.
// ---------------------------------------------------------------------------
__global__ void segsum_kernel(const float* __restrict__ z,
                              const u32* __restrict__ rowidx,
                              const u32* __restrict__ offsets,
                              float* __restrict__ asum) {
    int gw   = (blockIdx.x * 256 + threadIdx.x) >> 6;   // code id, 0..8191
    int lane = threadIdx.x & 63;
    u32 beg = offsets[gw], end = offsets[gw + 1];
    float acc = 0.f;
    for (u32 i = beg; i < end; ++i) {
        u32 r = rowidx[i];
        acc += z[(size_t)r * CODE_DIM + lane];
    }
    asum[(size_t)gw * CODE_DIM + lane] = acc;
}

// ---------------------------------------------------------------------------
// EMA finalize + losses. asum aliases out_weight (read-then-overwrite).
// ---------------------------------------------------------------------------
__global__ void finalize_kernel(const float* __restrict__ ema_count,
                                const float* __restrict__ ema_weight,
                                const float* __restrict__ usage,
                                const float* __restrict__ ws_counts,
                                const float* __restrict__ ws_loss,
                                float* __restrict__ out_codebook, float* __restrict__ out_count,
                                float* __restrict__ out_weight,   float* __restrict__ out_usage,
                                float* __restrict__ out_losses) {
    int gid = blockIdx.x * 256 + threadIdx.x;
    if (gid >= NUM_CODES * CODE_DIM) return;
    int c = gid >> 6;
    float cnt  = ws_counts[c];
    float ncnt = 0.99f * ema_count[c] + 0.01f * cnt;
    float nw   = 0.99f * ema_weight[gid] + 0.01f * out_weight[gid];  // asum alias
    out_weight[gid]   = nw;
    out_codebook[gid] = nw / (ncnt + 1e-5f);
    if ((gid & 63) == 0) {
        out_count[c] = ncnt;
        out_usage[c] = usage[c] + cnt;
    }
    if (gid == 0) {
        float s = ws_loss[0] * (1.0f / ((float)BATCH * (float)CODE_DIM));
        out_losses[0] = s;
        out_losses[1] = s;
        out_losses[2] = fmaf(0.25f, s, s);
    }
}

// ---------------------------------------------------------------------------
extern "C" void kernel_launch(void* const* d_in, const int* in_sizes, int n_in,
                              void* d_out, int out_size, void* d_ws, size_t ws_size,
                              hipStream_t stream) {
    const float* z     = (const float*)d_in[0];
    const float* cb    = (const float*)d_in[1];
    const float* emac  = (const float*)d_in[2];
    const float* emaw  = (const float*)d_in[3];
    const float* usage = (const float*)d_in[4];

    float* out = (float*)d_out;
    float* o_zq    = out;                    // 4194304
    float* o_codes = out + 4194304;          // 65536
    float* o_loss  = out + 4194304 + 65536;  // 3
    float* o_cb    = o_loss + 3;             // 524288 (scratch until finalize)
    float* o_cnt   = o_cb + 524288;          // 8192
    float* o_w     = o_cnt + 8192;           // 524288 (asum, then weight)
    float* o_use   = o_w + 524288;           // 8192

    // sort scratch inside o_cb region (2 MB; finalize overwrites it last)
    u32* rowidx  = (u32*)o_cb;               // [0, 65536)
    u32* offsets = rowidx + 65536;           // [65536, 73729)
    u32* cursor  = rowidx + 81920;           // [81920, 90112)

    char*  wsb     = (char*)d_ws;
    float* ws_csq  = (float*)(wsb + WS_CSQ_OFF);
    float* ws_cnt  = (float*)(wsb + WS_CNT_OFF);
    char*  ws_cbh  = wsb + WS_CBH_OFF;
    char*  ws_cbl  = wsb + WS_CBL_OFF;
    float* ws_loss = (float*)(wsb + WS_LOSS_OFF);

    hipMemsetAsync(wsb + WS_CNT_OFF, 0, 32768, stream);   // counts histogram
    hipMemsetAsync(wsb + WS_LOSS_OFF, 0, 4, stream);      // loss accumulator

    split_cb_kernel<<<256, 256, 0, stream>>>(cb, ws_cbh, ws_cbl, ws_csq);
    argmin_mfma_kernel<<<512, 256, 0, stream>>>(z, ws_cbh, ws_cbl, ws_csq,
                                                o_codes, ws_cnt);
    scan_kernel<<<1, 1024, 0, stream>>>(ws_cnt, offsets, cursor);
    scatter_kernel<<<BATCH * 4 / 256, 256, 0, stream>>>(z, cb, o_codes, o_zq,
                                                        cursor, rowidx, ws_loss);
    segsum_kernel<<<NUM_CODES * 64 / 256, 256, 0, stream>>>(z, rowidx, offsets, o_w);
    finalize_kernel<<<NUM_CODES * CODE_DIM / 256, 256, 0, stream>>>(
        emac, emaw, usage, ws_cnt, ws_loss,
        o_cb, o_cnt, o_w, o_use, o_loss);
}